// Round 1
// baseline (4885.380 us; speedup 1.0000x reference)
//
#include <hip/hip_runtime.h>

#define HID 64
#define NGRAPHS 64
#define LIN_NODES 32

// ---------------- degree count ----------------
__global__ void k_deg(const int* __restrict__ src, const int* __restrict__ dst,
                      int* __restrict__ degO, int* __restrict__ degI, int E) {
  int e = blockIdx.x * 256 + threadIdx.x;
  if (e >= E) return;
  atomicAdd(&degO[src[e]], 1);
  atomicAdd(&degI[dst[e]], 1);
}

// ---------------- norm = clip(deg,1)^-0.5 ----------------
__global__ void k_norm(const int* __restrict__ degO, const int* __restrict__ degI,
                       float* __restrict__ nO, float* __restrict__ nI, int N) {
  int n = blockIdx.x * 256 + threadIdx.x;
  if (n >= N) return;
  int o = degO[n] > 1 ? degO[n] : 1;
  int i = degI[n] > 1 ? degI[n] : 1;
  nO[n] = rsqrtf((float)o);
  nI[n] = rsqrtf((float)i);
}

// ---------------- embedding gather ----------------
__global__ void k_embed(const int* __restrict__ feat, const float* __restrict__ emb,
                        float* __restrict__ h, int N) {
  int t = blockIdx.x * 256 + threadIdx.x;
  int n = t >> 4, q = t & 15;
  if (n >= N) return;
  *(float4*)(h + (size_t)n * HID + q * 4) =
      *(const float4*)(emb + (size_t)feat[n] * HID + q * 4);
}

// ---------------- edge gather + scatter-add ----------------
// msg = h[src] * norm_out[src], atomically accumulated at agg[dst].
// 16 threads per edge, one float4 each.
__global__ __launch_bounds__(256) void k_scatter(
    const float* __restrict__ h, const float* __restrict__ nO,
    const int* __restrict__ src, const int* __restrict__ dst,
    float* __restrict__ agg, int E) {
  long long t = (long long)blockIdx.x * 256 + threadIdx.x;
  int e = (int)(t >> 4), q = (int)(t & 15);
  if (e >= E) return;
  int s = src[e], d = dst[e];
  float sc = nO[s];
  float4 v = *(const float4*)(h + (size_t)s * HID + q * 4);
  float* o = agg + (size_t)d * HID + q * 4;
  unsafeAtomicAdd(o + 0, v.x * sc);
  unsafeAtomicAdd(o + 1, v.y * sc);
  unsafeAtomicAdd(o + 2, v.z * sc);
  unsafeAtomicAdd(o + 3, v.w * sc);
}

// ---------------- x = agg*norm_in; out = relu(x @ W + b) ----------------
__global__ __launch_bounds__(256) void k_linear(
    const float* __restrict__ agg, const float* __restrict__ nI,
    const float* __restrict__ W, const float* __restrict__ b,
    float* __restrict__ out, int N) {
  __shared__ float Ws[HID * HID];      // 16 KB
  __shared__ float xs[LIN_NODES * HID]; // 8 KB
  int t = threadIdx.x;
  // load W (4096 floats, 256 threads * 4 floats * 4 iters)
  for (int i = t * 4; i < HID * HID; i += 256 * 4)
    *(float4*)(Ws + i) = *(const float4*)(W + i);
  int n0 = blockIdx.x * LIN_NODES;
  // load x tile (2048 floats)
  for (int i = t * 4; i < LIN_NODES * HID; i += 256 * 4) {
    int n = n0 + (i >> 6);
    float4 v = make_float4(0.f, 0.f, 0.f, 0.f);
    if (n < N) {
      v = *(const float4*)(agg + (size_t)n * HID + (i & 63));
      float s = nI[n];
      v.x *= s; v.y *= s; v.z *= s; v.w *= s;
    }
    *(float4*)(xs + i) = v;
  }
  __syncthreads();
  int j = t & 63, rg = t >> 6; // wave handles 8 nodes, lane j = output col
  float bj = b[j];
  for (int r = 0; r < LIN_NODES / 4; ++r) {
    int node = rg * (LIN_NODES / 4) + r;
    float acc = bj;
#pragma unroll
    for (int k = 0; k < HID; ++k)
      acc = fmaf(xs[node * HID + k], Ws[k * HID + j], acc);
    int n = n0 + node;
    if (n < N) out[(size_t)n * HID + j] = fmaxf(acc, 0.f);
  }
}

// ---------------- per-graph counts ----------------
__global__ void k_count(const int* __restrict__ gid, int* __restrict__ cnt, int N) {
  int n = blockIdx.x * 256 + threadIdx.x;
  if (n >= N) return;
  atomicAdd(&cnt[gid[n]], 1);
}

// ---------------- per-graph sum (graph_ids sorted -> run-length acc) ----------------
__global__ __launch_bounds__(256) void k_pool(
    const float* __restrict__ h, const int* __restrict__ gid,
    float* __restrict__ sums, int N) {
  int t = threadIdx.x;
  int j = t & 63, sub = t >> 6;
  int base = blockIdx.x * 256 + sub * 64; // this wave's 64-node chunk
  int cur = -1;
  float acc = 0.f;
  for (int i = 0; i < 64; ++i) {
    int n = base + i;
    if (n >= N) break;
    int g = gid[n];
    float v = h[(size_t)n * HID + j];
    if (g != cur) {
      if (cur >= 0) unsafeAtomicAdd(&sums[cur * HID + j], acc);
      cur = g;
      acc = v;
    } else {
      acc += v;
    }
  }
  if (cur >= 0) unsafeAtomicAdd(&sums[cur * HID + j], acc);
}

// ---------------- mean ----------------
__global__ void k_div(const float* __restrict__ sums, const int* __restrict__ cnt,
                      float* __restrict__ out) {
  int i = blockIdx.x * 256 + threadIdx.x;
  if (i >= NGRAPHS * HID) return;
  float c = (float)cnt[i >> 6];
  out[i] = sums[i] / fmaxf(c, 1.f);
}

extern "C" void kernel_launch(void* const* d_in, const int* in_sizes, int n_in,
                              void* d_out, int out_size, void* d_ws, size_t ws_size,
                              hipStream_t stream) {
  const int* node_feat = (const int*)d_in[0];
  const int* src = (const int*)d_in[1];
  const int* dst = (const int*)d_in[2];
  const int* gid = (const int*)d_in[3];
  const float* emb = (const float*)d_in[4];
  const float* W[3] = {(const float*)d_in[5], (const float*)d_in[7], (const float*)d_in[9]};
  const float* b[3] = {(const float*)d_in[6], (const float*)d_in[8], (const float*)d_in[10]};
  float* out = (float*)d_out;
  int N = in_sizes[0];
  int E = in_sizes[1];

  char* ws = (char*)d_ws;
  size_t off = 0;
  auto alloc = [&](size_t bytes) {
    char* p = ws + off;
    off = (off + bytes + 255) & ~(size_t)255;
    return p;
  };
  int* degO = (int*)alloc((size_t)N * 4);
  int* degI = (int*)alloc((size_t)N * 4);
  float* nO = (float*)alloc((size_t)N * 4);
  float* nI = (float*)alloc((size_t)N * 4);
  float* h0 = (float*)alloc((size_t)N * HID * 4);
  float* h1 = (float*)alloc((size_t)N * HID * 4);
  float* sums = (float*)alloc(NGRAPHS * HID * 4);
  int* cnt = (int*)alloc(NGRAPHS * 4);

  hipMemsetAsync(degO, 0, (size_t)N * 4, stream);
  hipMemsetAsync(degI, 0, (size_t)N * 4, stream);
  hipMemsetAsync(sums, 0, NGRAPHS * HID * 4, stream);
  hipMemsetAsync(cnt, 0, NGRAPHS * 4, stream);

  k_deg<<<(E + 255) / 256, 256, 0, stream>>>(src, dst, degO, degI, E);
  k_norm<<<(N + 255) / 256, 256, 0, stream>>>(degO, degI, nO, nI, N);
  k_embed<<<((size_t)N * 16 + 255) / 256, 256, 0, stream>>>(node_feat, emb, h0, N);

  for (int L = 0; L < 3; ++L) {
    hipMemsetAsync(h1, 0, (size_t)N * HID * 4, stream);
    k_scatter<<<((size_t)E * 16 + 255) / 256, 256, 0, stream>>>(h0, nO, src, dst, h1, E);
    k_linear<<<(N + LIN_NODES - 1) / LIN_NODES, 256, 0, stream>>>(h1, nI, W[L], b[L], h0, N);
  }

  k_count<<<(N + 255) / 256, 256, 0, stream>>>(gid, cnt, N);
  k_pool<<<(N + 255) / 256, 256, 0, stream>>>(h0, gid, sums, N);
  k_div<<<(NGRAPHS * HID + 255) / 256, 256, 0, stream>>>(sums, cnt, out);
}

// Round 2
// 1033.940 us; speedup vs baseline: 4.7250x; 4.7250x over previous
//
#include <hip/hip_runtime.h>

#define HID 64
#define NGRAPHS 64
#define LIN_NODES 32

// ---------------- degree count ----------------
__global__ void k_deg(const int* __restrict__ src, const int* __restrict__ dst,
                      int* __restrict__ degO, int* __restrict__ degI, int E) {
  int e = blockIdx.x * 256 + threadIdx.x;
  if (e >= E) return;
  atomicAdd(&degO[src[e]], 1);
  atomicAdd(&degI[dst[e]], 1);
}

// ---------------- norm = clip(deg,1)^-0.5 ----------------
__global__ void k_norm(const int* __restrict__ degO, const int* __restrict__ degI,
                       float* __restrict__ nO, float* __restrict__ nI, int N) {
  int n = blockIdx.x * 256 + threadIdx.x;
  if (n >= N) return;
  int o = degO[n] > 1 ? degO[n] : 1;
  int i = degI[n] > 1 ? degI[n] : 1;
  nO[n] = rsqrtf((float)o);
  nI[n] = rsqrtf((float)i);
}

// ---------------- CSR build: per-256-block inclusive scan ----------------
__global__ void k_scan1(const int* __restrict__ deg, int* __restrict__ excl,
                        int* __restrict__ blksum, int N) {
  __shared__ int s[256];
  int t = threadIdx.x;
  int i = blockIdx.x * 256 + t;
  int v = (i < N) ? deg[i] : 0;
  s[t] = v;
  __syncthreads();
  for (int o = 1; o < 256; o <<= 1) {
    int x = (t >= o) ? s[t - o] : 0;
    __syncthreads();
    s[t] += x;
    __syncthreads();
  }
  if (i < N) excl[i] = s[t] - v;          // exclusive within block
  if (t == 255) blksum[blockIdx.x] = s[255];
}

// single-block exclusive scan of block sums (nb <= 512)
__global__ void k_scan2(int* __restrict__ blksum, int nb) {
  __shared__ int s[512];
  int t = threadIdx.x;
  int v = (t < nb) ? blksum[t] : 0;
  s[t] = v;
  __syncthreads();
  for (int o = 1; o < 512; o <<= 1) {
    int x = (t >= o) ? s[t - o] : 0;
    __syncthreads();
    s[t] += x;
    __syncthreads();
  }
  if (t < nb) blksum[t] = s[t] - v;       // exclusive
}

__global__ void k_scan3(int* __restrict__ excl, const int* __restrict__ blksum, int N) {
  int i = blockIdx.x * 256 + threadIdx.x;
  if (i < N) excl[i] += blksum[blockIdx.x];
}

// bucket-fill: csr_src[off[dst]++] = src   (int atomics only, once per call)
__global__ void k_fill(const int* __restrict__ src, const int* __restrict__ dst,
                       const int* __restrict__ off, int* __restrict__ cur,
                       int* __restrict__ csr, int E) {
  int e = blockIdx.x * 256 + threadIdx.x;
  if (e >= E) return;
  int d = dst[e];
  int p = off[d] + atomicAdd(&cur[d], 1);
  csr[p] = src[e];
}

// ---------------- embedding gather, pre-scaled by norm_out ----------------
__global__ void k_embed(const int* __restrict__ feat, const float* __restrict__ emb,
                        const float* __restrict__ nO, float* __restrict__ h, int N) {
  int t = blockIdx.x * 256 + threadIdx.x;
  int n = t >> 4, q = t & 15;
  if (n >= N) return;
  float4 v = *(const float4*)(emb + (size_t)feat[n] * HID + q * 4);
  float s = nO[n];
  v.x *= s; v.y *= s; v.z *= s; v.w *= s;
  *(float4*)(h + (size_t)n * HID + q * 4) = v;
}

// ---------------- per-dst gather: agg[n] = sum over in-edges of hs[src] ----------------
// hs is already scaled by norm_out. 16 lanes per node, one float4 each. No atomics.
__global__ __launch_bounds__(256) void k_gather(
    const float* __restrict__ hs, const int* __restrict__ csr,
    const int* __restrict__ off, const int* __restrict__ deg,
    float* __restrict__ agg, int N) {
  long long t = (long long)blockIdx.x * 256 + threadIdx.x;
  int n = (int)(t >> 4), q = (int)(t & 15);
  if (n >= N) return;
  int r0 = off[n], d = deg[n];
  float4 acc = make_float4(0.f, 0.f, 0.f, 0.f);
  int i = 0;
  for (; i + 1 < d; i += 2) {
    int s0 = csr[r0 + i], s1 = csr[r0 + i + 1];
    float4 v0 = *(const float4*)(hs + (size_t)s0 * HID + q * 4);
    float4 v1 = *(const float4*)(hs + (size_t)s1 * HID + q * 4);
    acc.x += v0.x + v1.x; acc.y += v0.y + v1.y;
    acc.z += v0.z + v1.z; acc.w += v0.w + v1.w;
  }
  if (i < d) {
    int s0 = csr[r0 + i];
    float4 v0 = *(const float4*)(hs + (size_t)s0 * HID + q * 4);
    acc.x += v0.x; acc.y += v0.y; acc.z += v0.z; acc.w += v0.w;
  }
  *(float4*)(agg + (size_t)n * HID + q * 4) = acc;
}

// ---------------- x = agg*nI; out = relu(x @ W + b) * (postscale?) ----------------
__global__ __launch_bounds__(256) void k_linear(
    const float* __restrict__ agg, const float* __restrict__ nI,
    const float* __restrict__ W, const float* __restrict__ b,
    float* __restrict__ out, int N, const float* __restrict__ postscale) {
  __shared__ float Ws[HID * HID];        // 16 KB
  __shared__ float xs[LIN_NODES * HID];  // 8 KB
  int t = threadIdx.x;
  for (int i = t * 4; i < HID * HID; i += 256 * 4)
    *(float4*)(Ws + i) = *(const float4*)(W + i);
  int n0 = blockIdx.x * LIN_NODES;
  for (int i = t * 4; i < LIN_NODES * HID; i += 256 * 4) {
    int n = n0 + (i >> 6);
    float4 v = make_float4(0.f, 0.f, 0.f, 0.f);
    if (n < N) {
      v = *(const float4*)(agg + (size_t)n * HID + (i & 63));
      float s = nI[n];
      v.x *= s; v.y *= s; v.z *= s; v.w *= s;
    }
    *(float4*)(xs + i) = v;
  }
  __syncthreads();
  int j = t & 63, rg = t >> 6;  // wave handles 8 nodes, lane j = output col
  float bj = b[j];
  for (int r = 0; r < LIN_NODES / 4; ++r) {
    int node = rg * (LIN_NODES / 4) + r;
    float acc = bj;
#pragma unroll
    for (int k = 0; k < HID; ++k)
      acc = fmaf(xs[node * HID + k], Ws[k * HID + j], acc);
    int n = n0 + node;
    if (n < N) {
      float ps = postscale ? postscale[n] : 1.f;
      out[(size_t)n * HID + j] = fmaxf(acc, 0.f) * ps;
    }
  }
}

// ---------------- per-graph counts ----------------
__global__ void k_count(const int* __restrict__ gid, int* __restrict__ cnt, int N) {
  int n = blockIdx.x * 256 + threadIdx.x;
  if (n >= N) return;
  atomicAdd(&cnt[gid[n]], 1);
}

// ---------------- per-graph sum (graph_ids sorted -> run-length acc) ----------------
__global__ __launch_bounds__(256) void k_pool(
    const float* __restrict__ h, const int* __restrict__ gid,
    float* __restrict__ sums, int N) {
  int t = threadIdx.x;
  int j = t & 63, sub = t >> 6;
  int base = blockIdx.x * 256 + sub * 64;
  int cur = -1;
  float acc = 0.f;
  for (int i = 0; i < 64; ++i) {
    int n = base + i;
    if (n >= N) break;
    int g = gid[n];
    float v = h[(size_t)n * HID + j];
    if (g != cur) {
      if (cur >= 0) unsafeAtomicAdd(&sums[cur * HID + j], acc);
      cur = g;
      acc = v;
    } else {
      acc += v;
    }
  }
  if (cur >= 0) unsafeAtomicAdd(&sums[cur * HID + j], acc);
}

// ---------------- mean ----------------
__global__ void k_div(const float* __restrict__ sums, const int* __restrict__ cnt,
                      float* __restrict__ out) {
  int i = blockIdx.x * 256 + threadIdx.x;
  if (i >= NGRAPHS * HID) return;
  float c = (float)cnt[i >> 6];
  out[i] = sums[i] / fmaxf(c, 1.f);
}

extern "C" void kernel_launch(void* const* d_in, const int* in_sizes, int n_in,
                              void* d_out, int out_size, void* d_ws, size_t ws_size,
                              hipStream_t stream) {
  const int* node_feat = (const int*)d_in[0];
  const int* src = (const int*)d_in[1];
  const int* dst = (const int*)d_in[2];
  const int* gid = (const int*)d_in[3];
  const float* emb = (const float*)d_in[4];
  const float* W[3] = {(const float*)d_in[5], (const float*)d_in[7], (const float*)d_in[9]};
  const float* b[3] = {(const float*)d_in[6], (const float*)d_in[8], (const float*)d_in[10]};
  float* out = (float*)d_out;
  int N = in_sizes[0];
  int E = in_sizes[1];
  int nblk = (N + 255) / 256;  // 391 for N=100000

  char* ws = (char*)d_ws;
  size_t off_b = 0;
  auto alloc = [&](size_t bytes) {
    char* p = ws + off_b;
    off_b = (off_b + bytes + 255) & ~(size_t)255;
    return p;
  };
  int* degO = (int*)alloc((size_t)N * 4);   // reused as cursor after k_norm
  int* degI = (int*)alloc((size_t)N * 4);
  float* nO = (float*)alloc((size_t)N * 4);
  float* nI = (float*)alloc((size_t)N * 4);
  int* offs = (int*)alloc((size_t)N * 4);
  int* blks = (int*)alloc(512 * 4);
  int* csr = (int*)alloc((size_t)E * 4);
  float* h0 = (float*)alloc((size_t)N * HID * 4);
  float* agg = (float*)alloc((size_t)N * HID * 4);
  float* sums = (float*)alloc(NGRAPHS * HID * 4);
  int* cnt = (int*)alloc(NGRAPHS * 4);

  hipMemsetAsync(degO, 0, (size_t)N * 4, stream);
  hipMemsetAsync(degI, 0, (size_t)N * 4, stream);
  hipMemsetAsync(sums, 0, NGRAPHS * HID * 4, stream);
  hipMemsetAsync(cnt, 0, NGRAPHS * 4, stream);

  // degrees + norms
  k_deg<<<(E + 255) / 256, 256, 0, stream>>>(src, dst, degO, degI, E);
  k_norm<<<nblk, 256, 0, stream>>>(degO, degI, nO, nI, N);

  // CSR by dst: offs = exclusive_scan(degI); csr = src ids bucketed
  k_scan1<<<nblk, 256, 0, stream>>>(degI, offs, blks, N);
  k_scan2<<<1, 512, 0, stream>>>(blks, nblk);
  k_scan3<<<nblk, 256, 0, stream>>>(offs, blks, N);
  hipMemsetAsync(degO, 0, (size_t)N * 4, stream);  // degO becomes cursor
  k_fill<<<(E + 255) / 256, 256, 0, stream>>>(src, dst, offs, degO, csr, E);

  // h0 = emb[feat] * nO  (pre-scaled for layer-0 messages)
  k_embed<<<((size_t)N * 16 + 255) / 256, 256, 0, stream>>>(node_feat, emb, nO, h0, N);

  for (int L = 0; L < 3; ++L) {
    k_gather<<<((size_t)N * 16 + 255) / 256, 256, 0, stream>>>(h0, csr, offs, degI, agg, N);
    // layers 0,1: write relu(..)*nO (pre-scaled for next gather); layer 2: raw
    k_linear<<<(N + LIN_NODES - 1) / LIN_NODES, 256, 0, stream>>>(
        agg, nI, W[L], b[L], h0, N, (L < 2) ? nO : nullptr);
  }

  k_count<<<nblk, 256, 0, stream>>>(gid, cnt, N);
  k_pool<<<nblk, 256, 0, stream>>>(h0, gid, sums, N);
  k_div<<<(NGRAPHS * HID + 255) / 256, 256, 0, stream>>>(sums, cnt, out);
}

// Round 3
// 546.507 us; speedup vs baseline: 8.9393x; 1.8919x over previous
//
#include <hip/hip_runtime.h>

#define HID 64
#define NGRAPHS 64
#define LIN_NODES 32

// ---------------- degree count ----------------
__global__ void k_deg(const int* __restrict__ src, const int* __restrict__ dst,
                      int* __restrict__ degO, int* __restrict__ degI, int E) {
  int e = blockIdx.x * 256 + threadIdx.x;
  if (e >= E) return;
  atomicAdd(&degO[src[e]], 1);
  atomicAdd(&degI[dst[e]], 1);
}

// ---------------- norm = clip(deg,1)^-0.5 ----------------
__global__ void k_norm(const int* __restrict__ degO, const int* __restrict__ degI,
                       float* __restrict__ nO, float* __restrict__ nI, int N) {
  int n = blockIdx.x * 256 + threadIdx.x;
  if (n >= N) return;
  int o = degO[n] > 1 ? degO[n] : 1;
  int i = degI[n] > 1 ? degI[n] : 1;
  nO[n] = rsqrtf((float)o);
  nI[n] = rsqrtf((float)i);
}

// ---------------- CSR build: per-256-block inclusive scan ----------------
__global__ void k_scan1(const int* __restrict__ deg, int* __restrict__ excl,
                        int* __restrict__ blksum, int N) {
  __shared__ int s[256];
  int t = threadIdx.x;
  int i = blockIdx.x * 256 + t;
  int v = (i < N) ? deg[i] : 0;
  s[t] = v;
  __syncthreads();
  for (int o = 1; o < 256; o <<= 1) {
    int x = (t >= o) ? s[t - o] : 0;
    __syncthreads();
    s[t] += x;
    __syncthreads();
  }
  if (i < N) excl[i] = s[t] - v;          // exclusive within block
  if (t == 255) blksum[blockIdx.x] = s[255];
}

// single-block exclusive scan of block sums (nb <= 512)
__global__ void k_scan2(int* __restrict__ blksum, int nb) {
  __shared__ int s[512];
  int t = threadIdx.x;
  int v = (t < nb) ? blksum[t] : 0;
  s[t] = v;
  __syncthreads();
  for (int o = 1; o < 512; o <<= 1) {
    int x = (t >= o) ? s[t - o] : 0;
    __syncthreads();
    s[t] += x;
    __syncthreads();
  }
  if (t < nb) blksum[t] = s[t] - v;       // exclusive
}

__global__ void k_scan3(int* __restrict__ excl, const int* __restrict__ blksum, int N) {
  int i = blockIdx.x * 256 + threadIdx.x;
  if (i < N) excl[i] += blksum[blockIdx.x];
}

// bucket-fill: csr_src[off[dst]++] = src   (int atomics only, once per call)
__global__ void k_fill(const int* __restrict__ src, const int* __restrict__ dst,
                       const int* __restrict__ off, int* __restrict__ cur,
                       int* __restrict__ csr, int E) {
  int e = blockIdx.x * 256 + threadIdx.x;
  if (e >= E) return;
  int d = dst[e];
  int p = off[d] + atomicAdd(&cur[d], 1);
  csr[p] = src[e];
}

// ---------------- embedding gather, pre-scaled by norm_out ----------------
__global__ void k_embed(const int* __restrict__ feat, const float* __restrict__ emb,
                        const float* __restrict__ nO, float* __restrict__ h, int N) {
  int t = blockIdx.x * 256 + threadIdx.x;
  int n = t >> 4, q = t & 15;
  if (n >= N) return;
  float4 v = *(const float4*)(emb + (size_t)feat[n] * HID + q * 4);
  float s = nO[n];
  v.x *= s; v.y *= s; v.z *= s; v.w *= s;
  *(float4*)(h + (size_t)n * HID + q * 4) = v;
}

// ---------------- per-dst gather: agg[n] = sum over in-edges of hs[src] ----------------
// hs is already scaled by norm_out. 16 lanes per node, one float4 each. No atomics.
__global__ __launch_bounds__(256) void k_gather(
    const float* __restrict__ hs, const int* __restrict__ csr,
    const int* __restrict__ off, const int* __restrict__ deg,
    float* __restrict__ agg, int N) {
  long long t = (long long)blockIdx.x * 256 + threadIdx.x;
  int n = (int)(t >> 4), q = (int)(t & 15);
  if (n >= N) return;
  int r0 = off[n], d = deg[n];
  float4 acc = make_float4(0.f, 0.f, 0.f, 0.f);
  int i = 0;
  for (; i + 1 < d; i += 2) {
    int s0 = csr[r0 + i], s1 = csr[r0 + i + 1];
    float4 v0 = *(const float4*)(hs + (size_t)s0 * HID + q * 4);
    float4 v1 = *(const float4*)(hs + (size_t)s1 * HID + q * 4);
    acc.x += v0.x + v1.x; acc.y += v0.y + v1.y;
    acc.z += v0.z + v1.z; acc.w += v0.w + v1.w;
  }
  if (i < d) {
    int s0 = csr[r0 + i];
    float4 v0 = *(const float4*)(hs + (size_t)s0 * HID + q * 4);
    acc.x += v0.x; acc.y += v0.y; acc.z += v0.z; acc.w += v0.w;
  }
  *(float4*)(agg + (size_t)n * HID + q * 4) = acc;
}

// ---------------- x = agg*nI; out = relu(x @ W + b) * (postscale?) ----------------
__global__ __launch_bounds__(256) void k_linear(
    const float* __restrict__ agg, const float* __restrict__ nI,
    const float* __restrict__ W, const float* __restrict__ b,
    float* __restrict__ out, int N, const float* __restrict__ postscale) {
  __shared__ float Ws[HID * HID];        // 16 KB
  __shared__ float xs[LIN_NODES * HID];  // 8 KB
  int t = threadIdx.x;
  for (int i = t * 4; i < HID * HID; i += 256 * 4)
    *(float4*)(Ws + i) = *(const float4*)(W + i);
  int n0 = blockIdx.x * LIN_NODES;
  for (int i = t * 4; i < LIN_NODES * HID; i += 256 * 4) {
    int n = n0 + (i >> 6);
    float4 v = make_float4(0.f, 0.f, 0.f, 0.f);
    if (n < N) {
      v = *(const float4*)(agg + (size_t)n * HID + (i & 63));
      float s = nI[n];
      v.x *= s; v.y *= s; v.z *= s; v.w *= s;
    }
    *(float4*)(xs + i) = v;
  }
  __syncthreads();
  int j = t & 63, rg = t >> 6;  // wave handles 8 nodes, lane j = output col
  float bj = b[j];
  for (int r = 0; r < LIN_NODES / 4; ++r) {
    int node = rg * (LIN_NODES / 4) + r;
    float acc = bj;
#pragma unroll
    for (int k = 0; k < HID; ++k)
      acc = fmaf(xs[node * HID + k], Ws[k * HID + j], acc);
    int n = n0 + node;
    if (n < N) {
      float ps = postscale ? postscale[n] : 1.f;
      out[(size_t)n * HID + j] = fmaxf(acc, 0.f) * ps;
    }
  }
}

// ---------------- per-graph counts: LDS histogram, ~2 global atomics/block ----
__global__ __launch_bounds__(256) void k_count(const int* __restrict__ gid,
                                               int* __restrict__ cnt, int N) {
  __shared__ int h[NGRAPHS];
  int t = threadIdx.x;
  if (t < NGRAPHS) h[t] = 0;
  __syncthreads();
  int n = blockIdx.x * 256 + t;
  if (n < N) atomicAdd(&h[gid[n]], 1);   // LDS atomic; sorted gid -> 1-2 bins/block
  __syncthreads();
  if (t < NGRAPHS && h[t]) atomicAdd(&cnt[t], h[t]);
}

// ---------------- per-graph sum (graph_ids sorted -> run-length acc) ----------------
__global__ __launch_bounds__(256) void k_pool(
    const float* __restrict__ h, const int* __restrict__ gid,
    float* __restrict__ sums, int N) {
  int t = threadIdx.x;
  int j = t & 63, sub = t >> 6;
  int base = blockIdx.x * 256 + sub * 64;
  int cur = -1;
  float acc = 0.f;
  for (int i = 0; i < 64; ++i) {
    int n = base + i;
    if (n >= N) break;
    int g = gid[n];
    float v = h[(size_t)n * HID + j];
    if (g != cur) {
      if (cur >= 0) unsafeAtomicAdd(&sums[cur * HID + j], acc);
      cur = g;
      acc = v;
    } else {
      acc += v;
    }
  }
  if (cur >= 0) unsafeAtomicAdd(&sums[cur * HID + j], acc);
}

// ---------------- mean ----------------
__global__ void k_div(const float* __restrict__ sums, const int* __restrict__ cnt,
                      float* __restrict__ out) {
  int i = blockIdx.x * 256 + threadIdx.x;
  if (i >= NGRAPHS * HID) return;
  float c = (float)cnt[i >> 6];
  out[i] = sums[i] / fmaxf(c, 1.f);
}

extern "C" void kernel_launch(void* const* d_in, const int* in_sizes, int n_in,
                              void* d_out, int out_size, void* d_ws, size_t ws_size,
                              hipStream_t stream) {
  const int* node_feat = (const int*)d_in[0];
  const int* src = (const int*)d_in[1];
  const int* dst = (const int*)d_in[2];
  const int* gid = (const int*)d_in[3];
  const float* emb = (const float*)d_in[4];
  const float* W[3] = {(const float*)d_in[5], (const float*)d_in[7], (const float*)d_in[9]};
  const float* b[3] = {(const float*)d_in[6], (const float*)d_in[8], (const float*)d_in[10]};
  float* out = (float*)d_out;
  int N = in_sizes[0];
  int E = in_sizes[1];
  int nblk = (N + 255) / 256;  // 391 for N=100000

  char* ws = (char*)d_ws;
  size_t off_b = 0;
  auto alloc = [&](size_t bytes) {
    char* p = ws + off_b;
    off_b = (off_b + bytes + 255) & ~(size_t)255;
    return p;
  };
  int* degO = (int*)alloc((size_t)N * 4);   // reused as cursor after k_norm
  int* degI = (int*)alloc((size_t)N * 4);
  float* nO = (float*)alloc((size_t)N * 4);
  float* nI = (float*)alloc((size_t)N * 4);
  int* offs = (int*)alloc((size_t)N * 4);
  int* blks = (int*)alloc(512 * 4);
  int* csr = (int*)alloc((size_t)E * 4);
  float* h0 = (float*)alloc((size_t)N * HID * 4);
  float* agg = (float*)alloc((size_t)N * HID * 4);
  float* sums = (float*)alloc(NGRAPHS * HID * 4);
  int* cnt = (int*)alloc(NGRAPHS * 4);

  hipMemsetAsync(degO, 0, (size_t)N * 4, stream);
  hipMemsetAsync(degI, 0, (size_t)N * 4, stream);
  hipMemsetAsync(sums, 0, NGRAPHS * HID * 4, stream);
  hipMemsetAsync(cnt, 0, NGRAPHS * 4, stream);

  // degrees + norms
  k_deg<<<(E + 255) / 256, 256, 0, stream>>>(src, dst, degO, degI, E);
  k_norm<<<nblk, 256, 0, stream>>>(degO, degI, nO, nI, N);

  // CSR by dst: offs = exclusive_scan(degI); csr = src ids bucketed
  k_scan1<<<nblk, 256, 0, stream>>>(degI, offs, blks, N);
  k_scan2<<<1, 512, 0, stream>>>(blks, nblk);
  k_scan3<<<nblk, 256, 0, stream>>>(offs, blks, N);
  hipMemsetAsync(degO, 0, (size_t)N * 4, stream);  // degO becomes cursor
  k_fill<<<(E + 255) / 256, 256, 0, stream>>>(src, dst, offs, degO, csr, E);

  // h0 = emb[feat] * nO  (pre-scaled for layer-0 messages)
  k_embed<<<((size_t)N * 16 + 255) / 256, 256, 0, stream>>>(node_feat, emb, nO, h0, N);

  for (int L = 0; L < 3; ++L) {
    k_gather<<<((size_t)N * 16 + 255) / 256, 256, 0, stream>>>(h0, csr, offs, degI, agg, N);
    // layers 0,1: write relu(..)*nO (pre-scaled for next gather); layer 2: raw
    k_linear<<<(N + LIN_NODES - 1) / LIN_NODES, 256, 0, stream>>>(
        agg, nI, W[L], b[L], h0, N, (L < 2) ? nO : nullptr);
  }

  k_count<<<nblk, 256, 0, stream>>>(gid, cnt, N);
  k_pool<<<nblk, 256, 0, stream>>>(h0, gid, sums, N);
  k_div<<<(NGRAPHS * HID + 255) / 256, 256, 0, stream>>>(sums, cnt, out);
}

// Round 4
// 527.927 us; speedup vs baseline: 9.2539x; 1.0352x over previous
//
#include <hip/hip_runtime.h>

#define HID 64
#define NGRAPHS 64
#define LIN_NODES 32
#define NPART 8  // contention-spreading partials for histogram/cursor atomics

// ---------------- degree count into NPART partial histograms ----------------
// part layout [g*N + n] so partials for one node live in DIFFERENT cache lines.
__global__ void k_deg(const int* __restrict__ src, const int* __restrict__ dst,
                      int* __restrict__ dgO, int* __restrict__ dgI, int E, int N) {
  int e = blockIdx.x * 256 + threadIdx.x;
  if (e >= E) return;
  int g = e & (NPART - 1);
  atomicAdd(&dgO[g * N + src[e]], 1);
  atomicAdd(&dgI[g * N + dst[e]], 1);
}

// ---------------- reduce partials; norm = clip(deg,1)^-0.5; degT ----------------
__global__ void k_norm(const int* __restrict__ dgO, const int* __restrict__ dgI,
                       float* __restrict__ nO, float* __restrict__ nI,
                       int* __restrict__ degT, int N) {
  int n = blockIdx.x * 256 + threadIdx.x;
  if (n >= N) return;
  int o = 0, i = 0;
#pragma unroll
  for (int g = 0; g < NPART; ++g) {
    o += dgO[g * N + n];
    i += dgI[g * N + n];
  }
  degT[n] = i;
  nO[n] = rsqrtf((float)(o > 1 ? o : 1));
  nI[n] = rsqrtf((float)(i > 1 ? i : 1));
}

// ---------------- scan level 1 over transposed view [n][g] ----------------
// element i corresponds to (node i/NPART, group i%NPART); loads from dgI[g*N+n].
__global__ void k_scan1(const int* __restrict__ dgI, int* __restrict__ excl,
                        int* __restrict__ blksum, int N) {
  __shared__ int s[256];
  int t = threadIdx.x;
  int i = blockIdx.x * 256 + t;
  int M = N * NPART;
  int v = 0;
  if (i < M) v = dgI[(i & (NPART - 1)) * N + (i >> 3)];
  s[t] = v;
  __syncthreads();
  for (int o = 1; o < 256; o <<= 1) {
    int x = (t >= o) ? s[t - o] : 0;
    __syncthreads();
    s[t] += x;
    __syncthreads();
  }
  if (i < M) excl[i] = s[t] - v;          // exclusive within block
  if (t == 255) blksum[blockIdx.x] = s[255];
}

// single-block exclusive scan of up to 4096 block sums (1024 thr x 4 serial)
__global__ void k_scan2(int* __restrict__ blksum, int nb) {
  __shared__ int s[1024];
  int t = threadIdx.x;
  int base = t * 4;
  int v0 = base + 0 < nb ? blksum[base + 0] : 0;
  int v1 = base + 1 < nb ? blksum[base + 1] : 0;
  int v2 = base + 2 < nb ? blksum[base + 2] : 0;
  int v3 = base + 3 < nb ? blksum[base + 3] : 0;
  int sum = v0 + v1 + v2 + v3;
  s[t] = sum;
  __syncthreads();
  for (int o = 1; o < 1024; o <<= 1) {
    int x = (t >= o) ? s[t - o] : 0;
    __syncthreads();
    s[t] += x;
    __syncthreads();
  }
  int excl = s[t] - sum;
  if (base + 0 < nb) blksum[base + 0] = excl;
  if (base + 1 < nb) blksum[base + 1] = excl + v0;
  if (base + 2 < nb) blksum[base + 2] = excl + v0 + v1;
  if (base + 3 < nb) blksum[base + 3] = excl + v0 + v1 + v2;
}

__global__ void k_scan3(int* __restrict__ excl, const int* __restrict__ blksum, int M) {
  int i = blockIdx.x * 256 + threadIdx.x;
  if (i < M) excl[i] += blksum[blockIdx.x];
}

// bucket-fill with NPART partial cursors: csr[ offsE[d*NPART+g] + cur[g*N+d]++ ] = src
__global__ void k_fill(const int* __restrict__ src, const int* __restrict__ dst,
                       const int* __restrict__ offsE, int* __restrict__ cur,
                       int* __restrict__ csr, int E, int N) {
  int e = blockIdx.x * 256 + threadIdx.x;
  if (e >= E) return;
  int g = e & (NPART - 1);
  int d = dst[e];
  int p = offsE[d * NPART + g] + atomicAdd(&cur[g * N + d], 1);
  csr[p] = src[e];
}

// ---------------- embedding gather, pre-scaled by norm_out ----------------
__global__ void k_embed(const int* __restrict__ feat, const float* __restrict__ emb,
                        const float* __restrict__ nO, float* __restrict__ h, int N) {
  int t = blockIdx.x * 256 + threadIdx.x;
  int n = t >> 4, q = t & 15;
  if (n >= N) return;
  float4 v = *(const float4*)(emb + (size_t)feat[n] * HID + q * 4);
  float s = nO[n];
  v.x *= s; v.y *= s; v.z *= s; v.w *= s;
  *(float4*)(h + (size_t)n * HID + q * 4) = v;
}

// ---------------- per-dst gather: agg[n] = sum over in-edges of hs[src] ----------------
// hs pre-scaled by norm_out. 16 lanes per node, one float4 each. No atomics.
__global__ __launch_bounds__(256) void k_gather(
    const float* __restrict__ hs, const int* __restrict__ csr,
    const int* __restrict__ offsE, const int* __restrict__ degT,
    float* __restrict__ agg, int N) {
  long long t = (long long)blockIdx.x * 256 + threadIdx.x;
  int n = (int)(t >> 4), q = (int)(t & 15);
  if (n >= N) return;
  int r0 = offsE[n * NPART];  // node's full range is contiguous across its groups
  int d = degT[n];
  float4 acc = make_float4(0.f, 0.f, 0.f, 0.f);
  int i = 0;
  for (; i + 1 < d; i += 2) {
    int s0 = csr[r0 + i], s1 = csr[r0 + i + 1];
    float4 v0 = *(const float4*)(hs + (size_t)s0 * HID + q * 4);
    float4 v1 = *(const float4*)(hs + (size_t)s1 * HID + q * 4);
    acc.x += v0.x + v1.x; acc.y += v0.y + v1.y;
    acc.z += v0.z + v1.z; acc.w += v0.w + v1.w;
  }
  if (i < d) {
    int s0 = csr[r0 + i];
    float4 v0 = *(const float4*)(hs + (size_t)s0 * HID + q * 4);
    acc.x += v0.x; acc.y += v0.y; acc.z += v0.z; acc.w += v0.w;
  }
  *(float4*)(agg + (size_t)n * HID + q * 4) = acc;
}

// ---------------- x = agg*nI; out = relu(x @ W + b) * (postscale?) ----------------
__global__ __launch_bounds__(256) void k_linear(
    const float* __restrict__ agg, const float* __restrict__ nI,
    const float* __restrict__ W, const float* __restrict__ b,
    float* __restrict__ out, int N, const float* __restrict__ postscale) {
  __shared__ float Ws[HID * HID];        // 16 KB
  __shared__ float xs[LIN_NODES * HID];  // 8 KB
  int t = threadIdx.x;
  for (int i = t * 4; i < HID * HID; i += 256 * 4)
    *(float4*)(Ws + i) = *(const float4*)(W + i);
  int n0 = blockIdx.x * LIN_NODES;
  for (int i = t * 4; i < LIN_NODES * HID; i += 256 * 4) {
    int n = n0 + (i >> 6);
    float4 v = make_float4(0.f, 0.f, 0.f, 0.f);
    if (n < N) {
      v = *(const float4*)(agg + (size_t)n * HID + (i & 63));
      float s = nI[n];
      v.x *= s; v.y *= s; v.z *= s; v.w *= s;
    }
    *(float4*)(xs + i) = v;
  }
  __syncthreads();
  int j = t & 63, rg = t >> 6;  // wave handles 8 nodes, lane j = output col
  float bj = b[j];
  for (int r = 0; r < LIN_NODES / 4; ++r) {
    int node = rg * (LIN_NODES / 4) + r;
    float acc = bj;
#pragma unroll
    for (int k = 0; k < HID; ++k)
      acc = fmaf(xs[node * HID + k], Ws[k * HID + j], acc);
    int n = n0 + node;
    if (n < N) {
      float ps = postscale ? postscale[n] : 1.f;
      out[(size_t)n * HID + j] = fmaxf(acc, 0.f) * ps;
    }
  }
}

// ---------------- per-graph counts: LDS histogram, ~2 global atomics/block ----
__global__ __launch_bounds__(256) void k_count(const int* __restrict__ gid,
                                               int* __restrict__ cnt, int N) {
  __shared__ int h[NGRAPHS];
  int t = threadIdx.x;
  if (t < NGRAPHS) h[t] = 0;
  __syncthreads();
  int n = blockIdx.x * 256 + t;
  if (n < N) atomicAdd(&h[gid[n]], 1);
  __syncthreads();
  if (t < NGRAPHS && h[t]) atomicAdd(&cnt[t], h[t]);
}

// ---------------- per-graph sum (graph_ids sorted -> run-length acc) ----------------
__global__ __launch_bounds__(256) void k_pool(
    const float* __restrict__ h, const int* __restrict__ gid,
    float* __restrict__ sums, int N) {
  int t = threadIdx.x;
  int j = t & 63, sub = t >> 6;
  int base = blockIdx.x * 256 + sub * 64;
  int cur = -1;
  float acc = 0.f;
  for (int i = 0; i < 64; ++i) {
    int n = base + i;
    if (n >= N) break;
    int g = gid[n];
    float v = h[(size_t)n * HID + j];
    if (g != cur) {
      if (cur >= 0) unsafeAtomicAdd(&sums[cur * HID + j], acc);
      cur = g;
      acc = v;
    } else {
      acc += v;
    }
  }
  if (cur >= 0) unsafeAtomicAdd(&sums[cur * HID + j], acc);
}

// ---------------- mean ----------------
__global__ void k_div(const float* __restrict__ sums, const int* __restrict__ cnt,
                      float* __restrict__ out) {
  int i = blockIdx.x * 256 + threadIdx.x;
  if (i >= NGRAPHS * HID) return;
  float c = (float)cnt[i >> 6];
  out[i] = sums[i] / fmaxf(c, 1.f);
}

extern "C" void kernel_launch(void* const* d_in, const int* in_sizes, int n_in,
                              void* d_out, int out_size, void* d_ws, size_t ws_size,
                              hipStream_t stream) {
  const int* node_feat = (const int*)d_in[0];
  const int* src = (const int*)d_in[1];
  const int* dst = (const int*)d_in[2];
  const int* gid = (const int*)d_in[3];
  const float* emb = (const float*)d_in[4];
  const float* W[3] = {(const float*)d_in[5], (const float*)d_in[7], (const float*)d_in[9]};
  const float* b[3] = {(const float*)d_in[6], (const float*)d_in[8], (const float*)d_in[10]};
  float* out = (float*)d_out;
  int N = in_sizes[0];
  int E = in_sizes[1];
  int M = N * NPART;
  int nblk = (N + 255) / 256;
  int nblkM = (M + 255) / 256;  // 3125 for N=100000

  char* ws = (char*)d_ws;
  size_t off_b = 0;
  auto alloc = [&](size_t bytes) {
    char* p = ws + off_b;
    off_b = (off_b + bytes + 255) & ~(size_t)255;
    return p;
  };
  float* nO = (float*)alloc((size_t)N * 4);
  float* nI = (float*)alloc((size_t)N * 4);
  int* degT = (int*)alloc((size_t)N * 4);
  int* offsE = (int*)alloc((size_t)M * 4);   // 3.2 MB, exclusive scan, [n][g]
  int* blks = (int*)alloc(4096 * 4);
  int* csr = (int*)alloc((size_t)E * 4);
  float* h0 = (float*)alloc((size_t)N * HID * 4);
  float* agg = (float*)alloc((size_t)N * HID * 4);
  float* sums = (float*)alloc(NGRAPHS * HID * 4);
  int* cnt = (int*)alloc(NGRAPHS * 4);

  // partial histograms / cursors alias big buffers (dead before those are written)
  int* dgO = (int*)h0;        // M ints
  int* dgI = dgO + M;         // M ints  (6.4 MB total, h0 is 25.6 MB)
  int* cur = (int*)agg;       // M ints  (agg written first by k_gather, after k_fill)

  hipMemsetAsync(dgO, 0, (size_t)2 * M * 4, stream);
  hipMemsetAsync(sums, 0, NGRAPHS * HID * 4, stream);
  hipMemsetAsync(cnt, 0, NGRAPHS * 4, stream);

  // degrees (partials) + norms
  k_deg<<<(E + 255) / 256, 256, 0, stream>>>(src, dst, dgO, dgI, E, N);
  k_norm<<<nblk, 256, 0, stream>>>(dgO, dgI, nO, nI, degT, N);

  // CSR by dst: offsE = exclusive_scan over [n][g] view of dgI
  k_scan1<<<nblkM, 256, 0, stream>>>(dgI, offsE, blks, N);
  k_scan2<<<1, 1024, 0, stream>>>(blks, nblkM);
  k_scan3<<<nblkM, 256, 0, stream>>>(offsE, blks, M);
  hipMemsetAsync(cur, 0, (size_t)M * 4, stream);
  k_fill<<<(E + 255) / 256, 256, 0, stream>>>(src, dst, offsE, cur, csr, E, N);

  // h0 = emb[feat] * nO   (clobbers dgO/dgI — no longer needed)
  k_embed<<<((size_t)N * 16 + 255) / 256, 256, 0, stream>>>(node_feat, emb, nO, h0, N);

  for (int L = 0; L < 3; ++L) {
    k_gather<<<((size_t)N * 16 + 255) / 256, 256, 0, stream>>>(h0, csr, offsE, degT, agg, N);
    k_linear<<<(N + LIN_NODES - 1) / LIN_NODES, 256, 0, stream>>>(
        agg, nI, W[L], b[L], h0, N, (L < 2) ? nO : nullptr);
  }

  k_count<<<nblk, 256, 0, stream>>>(gid, cnt, N);
  k_pool<<<nblk, 256, 0, stream>>>(h0, gid, sums, N);
  k_div<<<(NGRAPHS * HID + 255) / 256, 256, 0, stream>>>(sums, cnt, out);
}

// Round 5
// 509.923 us; speedup vs baseline: 9.5806x; 1.0353x over previous
//
#include <hip/hip_runtime.h>

#define HID 64
#define NGRAPHS 64
#define LIN_NODES 32
#define NPART 8  // = number of XCDs on MI355X; partials are XCD-private

// Physical XCD id of the CU this wave runs on (gfx940+: HW_REG_XCC_ID = hwreg 20).
__device__ __forceinline__ int xcc_id() {
  return __builtin_amdgcn_s_getreg(20 | (0 << 6) | (31 << 11)) & (NPART - 1);
}

// ---------------- degree count into XCD-private partial histograms ----------
// dgX[g*N + n], g = physical XCD -> each partial array is owned by ONE XCD's L2,
// so workgroup-scope (non-device) atomics are safe and execute locally in L2.
// The in-degree atomic's return value is the edge's slot ticket within (g,d).
__global__ void k_deg(const int* __restrict__ src, const int* __restrict__ dst,
                      int* __restrict__ dgO, int* __restrict__ dgI,
                      unsigned short* __restrict__ gt, int E, int N) {
  int e = blockIdx.x * 256 + threadIdx.x;
  if (e >= E) return;
  int g = xcc_id();
  __hip_atomic_fetch_add(&dgO[g * N + src[e]], 1, __ATOMIC_RELAXED,
                         __HIP_MEMORY_SCOPE_WORKGROUP);
  int t = __hip_atomic_fetch_add(&dgI[g * N + dst[e]], 1, __ATOMIC_RELAXED,
                                 __HIP_MEMORY_SCOPE_WORKGROUP);
  gt[e] = (unsigned short)((g << 11) | t);   // in-degree < 2048 guaranteed
}

// ---------------- reduce partials; norm = clip(deg,1)^-0.5; degT ----------------
__global__ void k_norm(const int* __restrict__ dgO, const int* __restrict__ dgI,
                       float* __restrict__ nO, float* __restrict__ nI,
                       int* __restrict__ degT, int N) {
  int n = blockIdx.x * 256 + threadIdx.x;
  if (n >= N) return;
  int o = 0, i = 0;
#pragma unroll
  for (int g = 0; g < NPART; ++g) {
    o += dgO[g * N + n];
    i += dgI[g * N + n];
  }
  degT[n] = i;
  nO[n] = rsqrtf((float)(o > 1 ? o : 1));
  nI[n] = rsqrtf((float)(i > 1 ? i : 1));
}

// ---------------- scan level 1 over transposed view [n][g] ----------------
__global__ void k_scan1(const int* __restrict__ dgI, int* __restrict__ excl,
                        int* __restrict__ blksum, int N) {
  __shared__ int s[256];
  int t = threadIdx.x;
  int i = blockIdx.x * 256 + t;
  int M = N * NPART;
  int v = 0;
  if (i < M) v = dgI[(i & (NPART - 1)) * N + (i >> 3)];
  s[t] = v;
  __syncthreads();
  for (int o = 1; o < 256; o <<= 1) {
    int x = (t >= o) ? s[t - o] : 0;
    __syncthreads();
    s[t] += x;
    __syncthreads();
  }
  if (i < M) excl[i] = s[t] - v;          // exclusive within block
  if (t == 255) blksum[blockIdx.x] = s[255];
}

// single-block exclusive scan of up to 4096 block sums (1024 thr x 4 serial)
__global__ void k_scan2(int* __restrict__ blksum, int nb) {
  __shared__ int s[1024];
  int t = threadIdx.x;
  int base = t * 4;
  int v0 = base + 0 < nb ? blksum[base + 0] : 0;
  int v1 = base + 1 < nb ? blksum[base + 1] : 0;
  int v2 = base + 2 < nb ? blksum[base + 2] : 0;
  int v3 = base + 3 < nb ? blksum[base + 3] : 0;
  int sum = v0 + v1 + v2 + v3;
  s[t] = sum;
  __syncthreads();
  for (int o = 1; o < 1024; o <<= 1) {
    int x = (t >= o) ? s[t - o] : 0;
    __syncthreads();
    s[t] += x;
    __syncthreads();
  }
  int excl = s[t] - sum;
  if (base + 0 < nb) blksum[base + 0] = excl;
  if (base + 1 < nb) blksum[base + 1] = excl + v0;
  if (base + 2 < nb) blksum[base + 2] = excl + v0 + v1;
  if (base + 3 < nb) blksum[base + 3] = excl + v0 + v1 + v2;
}

__global__ void k_scan3(int* __restrict__ excl, const int* __restrict__ blksum, int M) {
  int i = blockIdx.x * 256 + threadIdx.x;
  if (i < M) excl[i] += blksum[blockIdx.x];
}

// bucket-fill, NO atomics: slot comes from the stored (g, ticket).
__global__ void k_fill(const int* __restrict__ src, const int* __restrict__ dst,
                       const unsigned short* __restrict__ gt,
                       const int* __restrict__ offsE, int* __restrict__ csr, int E) {
  int e = blockIdx.x * 256 + threadIdx.x;
  if (e >= E) return;
  int v = gt[e];
  int g = v >> 11, t = v & 2047;
  csr[offsE[dst[e] * NPART + g] + t] = src[e];
}

// ---------------- embedding gather, pre-scaled by norm_out ----------------
__global__ void k_embed(const int* __restrict__ feat, const float* __restrict__ emb,
                        const float* __restrict__ nO, float* __restrict__ h, int N) {
  int t = blockIdx.x * 256 + threadIdx.x;
  int n = t >> 4, q = t & 15;
  if (n >= N) return;
  float4 v = *(const float4*)(emb + (size_t)feat[n] * HID + q * 4);
  float s = nO[n];
  v.x *= s; v.y *= s; v.z *= s; v.w *= s;
  *(float4*)(h + (size_t)n * HID + q * 4) = v;
}

// ---------------- per-dst gather: agg[n] = sum over in-edges of hs[src] ----------------
__global__ __launch_bounds__(256) void k_gather(
    const float* __restrict__ hs, const int* __restrict__ csr,
    const int* __restrict__ offsE, const int* __restrict__ degT,
    float* __restrict__ agg, int N) {
  long long t = (long long)blockIdx.x * 256 + threadIdx.x;
  int n = (int)(t >> 4), q = (int)(t & 15);
  if (n >= N) return;
  int r0 = offsE[n * NPART];  // node's full range is contiguous across its groups
  int d = degT[n];
  float4 acc = make_float4(0.f, 0.f, 0.f, 0.f);
  int i = 0;
  for (; i + 1 < d; i += 2) {
    int s0 = csr[r0 + i], s1 = csr[r0 + i + 1];
    float4 v0 = *(const float4*)(hs + (size_t)s0 * HID + q * 4);
    float4 v1 = *(const float4*)(hs + (size_t)s1 * HID + q * 4);
    acc.x += v0.x + v1.x; acc.y += v0.y + v1.y;
    acc.z += v0.z + v1.z; acc.w += v0.w + v1.w;
  }
  if (i < d) {
    int s0 = csr[r0 + i];
    float4 v0 = *(const float4*)(hs + (size_t)s0 * HID + q * 4);
    acc.x += v0.x; acc.y += v0.y; acc.z += v0.z; acc.w += v0.w;
  }
  *(float4*)(agg + (size_t)n * HID + q * 4) = acc;
}

// ---------------- x = agg*nI; out = relu(x @ W + b) * (postscale?) ----------------
__global__ __launch_bounds__(256) void k_linear(
    const float* __restrict__ agg, const float* __restrict__ nI,
    const float* __restrict__ W, const float* __restrict__ b,
    float* __restrict__ out, int N, const float* __restrict__ postscale) {
  __shared__ float Ws[HID * HID];        // 16 KB
  __shared__ float xs[LIN_NODES * HID];  // 8 KB
  int t = threadIdx.x;
  for (int i = t * 4; i < HID * HID; i += 256 * 4)
    *(float4*)(Ws + i) = *(const float4*)(W + i);
  int n0 = blockIdx.x * LIN_NODES;
  for (int i = t * 4; i < LIN_NODES * HID; i += 256 * 4) {
    int n = n0 + (i >> 6);
    float4 v = make_float4(0.f, 0.f, 0.f, 0.f);
    if (n < N) {
      v = *(const float4*)(agg + (size_t)n * HID + (i & 63));
      float s = nI[n];
      v.x *= s; v.y *= s; v.z *= s; v.w *= s;
    }
    *(float4*)(xs + i) = v;
  }
  __syncthreads();
  int j = t & 63, rg = t >> 6;  // wave handles 8 nodes, lane j = output col
  float bj = b[j];
  for (int r = 0; r < LIN_NODES / 4; ++r) {
    int node = rg * (LIN_NODES / 4) + r;
    float acc = bj;
#pragma unroll
    for (int k = 0; k < HID; ++k)
      acc = fmaf(xs[node * HID + k], Ws[k * HID + j], acc);
    int n = n0 + node;
    if (n < N) {
      float ps = postscale ? postscale[n] : 1.f;
      out[(size_t)n * HID + j] = fmaxf(acc, 0.f) * ps;
    }
  }
}

// ---------------- per-graph counts: LDS histogram, ~2 global atomics/block ----
__global__ __launch_bounds__(256) void k_count(const int* __restrict__ gid,
                                               int* __restrict__ cnt, int N) {
  __shared__ int h[NGRAPHS];
  int t = threadIdx.x;
  if (t < NGRAPHS) h[t] = 0;
  __syncthreads();
  int n = blockIdx.x * 256 + t;
  if (n < N) atomicAdd(&h[gid[n]], 1);
  __syncthreads();
  if (t < NGRAPHS && h[t]) atomicAdd(&cnt[t], h[t]);
}

// ---------------- per-graph sum (graph_ids sorted -> run-length acc) ----------------
__global__ __launch_bounds__(256) void k_pool(
    const float* __restrict__ h, const int* __restrict__ gid,
    float* __restrict__ sums, int N) {
  int t = threadIdx.x;
  int j = t & 63, sub = t >> 6;
  int base = blockIdx.x * 256 + sub * 64;
  int cur = -1;
  float acc = 0.f;
  for (int i = 0; i < 64; ++i) {
    int n = base + i;
    if (n >= N) break;
    int g = gid[n];
    float v = h[(size_t)n * HID + j];
    if (g != cur) {
      if (cur >= 0) unsafeAtomicAdd(&sums[cur * HID + j], acc);
      cur = g;
      acc = v;
    } else {
      acc += v;
    }
  }
  if (cur >= 0) unsafeAtomicAdd(&sums[cur * HID + j], acc);
}

// ---------------- mean ----------------
__global__ void k_div(const float* __restrict__ sums, const int* __restrict__ cnt,
                      float* __restrict__ out) {
  int i = blockIdx.x * 256 + threadIdx.x;
  if (i >= NGRAPHS * HID) return;
  float c = (float)cnt[i >> 6];
  out[i] = sums[i] / fmaxf(c, 1.f);
}

extern "C" void kernel_launch(void* const* d_in, const int* in_sizes, int n_in,
                              void* d_out, int out_size, void* d_ws, size_t ws_size,
                              hipStream_t stream) {
  const int* node_feat = (const int*)d_in[0];
  const int* src = (const int*)d_in[1];
  const int* dst = (const int*)d_in[2];
  const int* gid = (const int*)d_in[3];
  const float* emb = (const float*)d_in[4];
  const float* W[3] = {(const float*)d_in[5], (const float*)d_in[7], (const float*)d_in[9]};
  const float* b[3] = {(const float*)d_in[6], (const float*)d_in[8], (const float*)d_in[10]};
  float* out = (float*)d_out;
  int N = in_sizes[0];
  int E = in_sizes[1];
  int M = N * NPART;
  int nblk = (N + 255) / 256;
  int nblkM = (M + 255) / 256;  // 3125 for N=100000

  char* ws = (char*)d_ws;
  size_t off_b = 0;
  auto alloc = [&](size_t bytes) {
    char* p = ws + off_b;
    off_b = (off_b + bytes + 255) & ~(size_t)255;
    return p;
  };
  float* nO = (float*)alloc((size_t)N * 4);
  float* nI = (float*)alloc((size_t)N * 4);
  int* degT = (int*)alloc((size_t)N * 4);
  int* offsE = (int*)alloc((size_t)M * 4);   // 3.2 MB, exclusive scan, [n][g]
  int* blks = (int*)alloc(4096 * 4);
  int* csr = (int*)alloc((size_t)E * 4);
  float* h0 = (float*)alloc((size_t)N * HID * 4);
  float* agg = (float*)alloc((size_t)N * HID * 4);
  float* sums = (float*)alloc(NGRAPHS * HID * 4);
  int* cnt = (int*)alloc(NGRAPHS * 4);

  // partial histograms + tickets alias big buffers (dead before those are written)
  int* dgO = (int*)h0;                       // M ints
  int* dgI = dgO + M;                        // M ints (6.4 MB total; h0 is 25.6 MB)
  unsigned short* gt = (unsigned short*)agg; // E ushorts (3.2 MB; agg written later)

  hipMemsetAsync(dgO, 0, (size_t)2 * M * 4, stream);
  hipMemsetAsync(sums, 0, NGRAPHS * HID * 4, stream);
  hipMemsetAsync(cnt, 0, NGRAPHS * 4, stream);

  // degrees (XCD-private partials, L2-local atomics) + tickets + norms
  k_deg<<<(E + 255) / 256, 256, 0, stream>>>(src, dst, dgO, dgI, gt, E, N);
  k_norm<<<nblk, 256, 0, stream>>>(dgO, dgI, nO, nI, degT, N);

  // CSR by dst: offsE = exclusive_scan over [n][g] view of dgI; fill w/o atomics
  k_scan1<<<nblkM, 256, 0, stream>>>(dgI, offsE, blks, N);
  k_scan2<<<1, 1024, 0, stream>>>(blks, nblkM);
  k_scan3<<<nblkM, 256, 0, stream>>>(offsE, blks, M);
  k_fill<<<(E + 255) / 256, 256, 0, stream>>>(src, dst, gt, offsE, csr, E);

  // h0 = emb[feat] * nO   (clobbers dgO/dgI — no longer needed)
  k_embed<<<((size_t)N * 16 + 255) / 256, 256, 0, stream>>>(node_feat, emb, nO, h0, N);

  for (int L = 0; L < 3; ++L) {
    k_gather<<<((size_t)N * 16 + 255) / 256, 256, 0, stream>>>(h0, csr, offsE, degT, agg, N);
    k_linear<<<(N + LIN_NODES - 1) / LIN_NODES, 256, 0, stream>>>(
        agg, nI, W[L], b[L], h0, N, (L < 2) ? nO : nullptr);
  }

  k_count<<<nblk, 256, 0, stream>>>(gid, cnt, N);
  k_pool<<<nblk, 256, 0, stream>>>(h0, gid, sums, N);
  k_div<<<(NGRAPHS * HID + 255) / 256, 256, 0, stream>>>(sums, cnt, out);
}

// Round 7
// 472.131 us; speedup vs baseline: 10.3475x; 1.0800x over previous
//
#include <hip/hip_runtime.h>

#define HID 64
#define NGRAPHS 64
#define LIN_NODES 32

// ---------------- degree count + ticket ----------------
// Plain device-scope atomics (R3/R4: scope/spreading don't help; cost is a flat
// memory-side transaction per atomic). The in-degree atomic's return value is
// the edge's slot within its dst node -> k_fill needs no atomics.
__global__ void k_deg(const int* __restrict__ src, const int* __restrict__ dst,
                      int* __restrict__ dgO, int* __restrict__ dgI,
                      unsigned short* __restrict__ gt, int E) {
  int e = blockIdx.x * 256 + threadIdx.x;
  if (e >= E) return;
  atomicAdd(&dgO[src[e]], 1);
  int t = atomicAdd(&dgI[dst[e]], 1);
  gt[e] = (unsigned short)t;   // in-degree << 65536
}

// ---------------- norms + block-level scan of in-degree (fused) ----------------
__global__ void k_norm_scan(const int* __restrict__ dgO, const int* __restrict__ dgI,
                            float* __restrict__ nO, float* __restrict__ nI,
                            int* __restrict__ excl, int* __restrict__ blksum, int N) {
  __shared__ int s[256];
  int t = threadIdx.x;
  int n = blockIdx.x * 256 + t;
  int di = 0;
  if (n < N) {
    int o = dgO[n];
    di = dgI[n];
    nO[n] = rsqrtf((float)(o > 1 ? o : 1));
    nI[n] = rsqrtf((float)(di > 1 ? di : 1));
  }
  s[t] = di;
  __syncthreads();
  for (int o = 1; o < 256; o <<= 1) {
    int x = (t >= o) ? s[t - o] : 0;
    __syncthreads();
    s[t] += x;
    __syncthreads();
  }
  if (n < N) excl[n] = s[t] - di;          // exclusive within block
  if (t == 255) blksum[blockIdx.x] = s[255];
}

// single-block exclusive scan of up to 4096 block sums (1024 thr x 4 serial)
__global__ void k_scan2(int* __restrict__ blksum, int nb) {
  __shared__ int s[1024];
  int t = threadIdx.x;
  int base = t * 4;
  int v0 = base + 0 < nb ? blksum[base + 0] : 0;
  int v1 = base + 1 < nb ? blksum[base + 1] : 0;
  int v2 = base + 2 < nb ? blksum[base + 2] : 0;
  int v3 = base + 3 < nb ? blksum[base + 3] : 0;
  int sum = v0 + v1 + v2 + v3;
  s[t] = sum;
  __syncthreads();
  for (int o = 1; o < 1024; o <<= 1) {
    int x = (t >= o) ? s[t - o] : 0;
    __syncthreads();
    s[t] += x;
    __syncthreads();
  }
  int excl = s[t] - sum;
  if (base + 0 < nb) blksum[base + 0] = excl;
  if (base + 1 < nb) blksum[base + 1] = excl + v0;
  if (base + 2 < nb) blksum[base + 2] = excl + v0 + v1;
  if (base + 3 < nb) blksum[base + 3] = excl + v0 + v1 + v2;
}

__global__ void k_scan3(int* __restrict__ excl, const int* __restrict__ blksum, int N) {
  int i = blockIdx.x * 256 + threadIdx.x;
  if (i < N) excl[i] += blksum[blockIdx.x];
}

// bucket-fill, NO atomics: slot = offs[dst] + stored ticket.
__global__ void k_fill(const int* __restrict__ src, const int* __restrict__ dst,
                       const unsigned short* __restrict__ gt,
                       const int* __restrict__ offs, int* __restrict__ csr, int E) {
  int e = blockIdx.x * 256 + threadIdx.x;
  if (e >= E) return;
  csr[offs[dst[e]] + gt[e]] = src[e];
}

// ---------------- embedding gather, pre-scaled by norm_out ----------------
__global__ void k_embed(const int* __restrict__ feat, const float* __restrict__ emb,
                        const float* __restrict__ nO, float* __restrict__ h, int N) {
  int t = blockIdx.x * 256 + threadIdx.x;
  int n = t >> 4, q = t & 15;
  if (n >= N) return;
  float4 v = *(const float4*)(emb + (size_t)feat[n] * HID + q * 4);
  float s = nO[n];
  v.x *= s; v.y *= s; v.z *= s; v.w *= s;
  *(float4*)(h + (size_t)n * HID + q * 4) = v;
}

// ---------------- fused gather + linear ----------------
// Per block: 32 nodes. Phase A: 8 lanes/node gather sum(hs[src]) directly into
// the LDS x-tile (scaled by nI). Phase B: 64x64 matmul, relu, optional postscale.
// Reads hs randomly across the whole array -> MUST write to a different buffer.
__global__ __launch_bounds__(256) void k_gl(
    const float* __restrict__ hs, const int* __restrict__ csr,
    const int* __restrict__ offs, const int* __restrict__ deg,
    const float* __restrict__ nI, const float* __restrict__ W,
    const float* __restrict__ b, float* __restrict__ out,
    int N, const float* __restrict__ postscale) {
  __shared__ float Ws[HID * HID];        // 16 KB
  __shared__ float xs[LIN_NODES * HID];  // 8 KB
  int t = threadIdx.x;
  for (int i = t * 4; i < HID * HID; i += 256 * 4)
    *(float4*)(Ws + i) = *(const float4*)(W + i);

  int n0 = blockIdx.x * LIN_NODES;
  int gnode = t >> 3, q = t & 7;         // 32 nodes x 8 lanes; lane q = cols q*8..q*8+7
  int n = n0 + gnode;
  float4 a0 = make_float4(0.f, 0.f, 0.f, 0.f), a1 = a0;
  if (n < N) {
    int r0 = offs[n], d = deg[n];
    const float* hq = hs + q * 8;
    int i = 0;
    for (; i + 1 < d; i += 2) {
      int s0 = csr[r0 + i], s1 = csr[r0 + i + 1];
      const float* p0 = hq + (size_t)s0 * HID;
      const float* p1 = hq + (size_t)s1 * HID;
      float4 v0 = *(const float4*)(p0);
      float4 v1 = *(const float4*)(p0 + 4);
      float4 w0 = *(const float4*)(p1);
      float4 w1 = *(const float4*)(p1 + 4);
      a0.x += v0.x + w0.x; a0.y += v0.y + w0.y;
      a0.z += v0.z + w0.z; a0.w += v0.w + w0.w;
      a1.x += v1.x + w1.x; a1.y += v1.y + w1.y;
      a1.z += v1.z + w1.z; a1.w += v1.w + w1.w;
    }
    if (i < d) {
      int s0 = csr[r0 + i];
      const float* p0 = hq + (size_t)s0 * HID;
      float4 v0 = *(const float4*)(p0);
      float4 v1 = *(const float4*)(p0 + 4);
      a0.x += v0.x; a0.y += v0.y; a0.z += v0.z; a0.w += v0.w;
      a1.x += v1.x; a1.y += v1.y; a1.z += v1.z; a1.w += v1.w;
    }
    float sc = nI[n];
    a0.x *= sc; a0.y *= sc; a0.z *= sc; a0.w *= sc;
    a1.x *= sc; a1.y *= sc; a1.z *= sc; a1.w *= sc;
  }
  *(float4*)(xs + gnode * HID + q * 8) = a0;
  *(float4*)(xs + gnode * HID + q * 8 + 4) = a1;
  __syncthreads();

  int j = t & 63, rg = t >> 6;  // wave handles 8 nodes, lane j = output col
  float bj = b[j];
  for (int r = 0; r < LIN_NODES / 4; ++r) {
    int node = rg * (LIN_NODES / 4) + r;
    float acc = bj;
#pragma unroll
    for (int k = 0; k < HID; ++k)
      acc = fmaf(xs[node * HID + k], Ws[k * HID + j], acc);
    int nn = n0 + node;
    if (nn < N) {
      float ps = postscale ? postscale[nn] : 1.f;
      out[(size_t)nn * HID + j] = fmaxf(acc, 0.f) * ps;
    }
  }
}

// ---------------- per-graph sum + count (gid sorted -> run-length, wave-uniform) ----
__global__ __launch_bounds__(256) void k_pool(
    const float* __restrict__ h, const int* __restrict__ gid,
    float* __restrict__ sums, int* __restrict__ cnt, int N) {
  int t = threadIdx.x;
  int j = t & 63, sub = t >> 6;
  int base = blockIdx.x * 256 + sub * 64;
  int cur = -1, rl = 0;
  float acc = 0.f;
  for (int i = 0; i < 64; ++i) {
    int n = base + i;
    if (n >= N) break;
    int g = gid[n];
    float v = h[(size_t)n * HID + j];
    if (g != cur) {
      if (cur >= 0) {
        unsafeAtomicAdd(&sums[cur * HID + j], acc);
        if (j == 0) atomicAdd(&cnt[cur], rl);
      }
      cur = g; acc = v; rl = 1;
    } else {
      acc += v; ++rl;
    }
  }
  if (cur >= 0) {
    unsafeAtomicAdd(&sums[cur * HID + j], acc);
    if (j == 0) atomicAdd(&cnt[cur], rl);
  }
}

// ---------------- mean ----------------
__global__ void k_div(const float* __restrict__ sums, const int* __restrict__ cnt,
                      float* __restrict__ out) {
  int i = blockIdx.x * 256 + threadIdx.x;
  if (i >= NGRAPHS * HID) return;
  float c = (float)cnt[i >> 6];
  out[i] = sums[i] / fmaxf(c, 1.f);
}

extern "C" void kernel_launch(void* const* d_in, const int* in_sizes, int n_in,
                              void* d_out, int out_size, void* d_ws, size_t ws_size,
                              hipStream_t stream) {
  const int* node_feat = (const int*)d_in[0];
  const int* src = (const int*)d_in[1];
  const int* dst = (const int*)d_in[2];
  const int* gid = (const int*)d_in[3];
  const float* emb = (const float*)d_in[4];
  const float* W[3] = {(const float*)d_in[5], (const float*)d_in[7], (const float*)d_in[9]};
  const float* b[3] = {(const float*)d_in[6], (const float*)d_in[8], (const float*)d_in[10]};
  float* out = (float*)d_out;
  int N = in_sizes[0];
  int E = in_sizes[1];
  int nblk = (N + 255) / 256;  // 391 for N=100000

  char* ws = (char*)d_ws;
  size_t off_b = 0;
  auto alloc = [&](size_t bytes) {
    char* p = ws + off_b;
    off_b = (off_b + bytes + 255) & ~(size_t)255;
    return p;
  };
  // dgO and dgI MUST be one contiguous block: the zeroing memset covers 2*N ints
  // (R5 crash: 256B alloc padding left a 128B tail of dgI poisoned).
  int* dgO = (int*)alloc((size_t)2 * N * 4);
  int* dgI = dgO + N;
  float* nO = (float*)alloc((size_t)N * 4);
  float* nI = (float*)alloc((size_t)N * 4);
  int* offs = (int*)alloc((size_t)N * 4);
  int* blks = (int*)alloc(4096 * 4);
  unsigned short* gt = (unsigned short*)alloc((size_t)E * 2);
  int* csr = (int*)alloc((size_t)E * 4);
  float* h0 = (float*)alloc((size_t)N * HID * 4);
  float* h1 = (float*)alloc((size_t)N * HID * 4);
  float* sums = (float*)alloc(NGRAPHS * HID * 4);
  int* cnt = (int*)alloc(NGRAPHS * 4);

  hipMemsetAsync(dgO, 0, (size_t)2 * N * 4, stream);
  hipMemsetAsync(sums, 0, NGRAPHS * HID * 4, stream);
  hipMemsetAsync(cnt, 0, NGRAPHS * 4, stream);

  // degrees + tickets
  k_deg<<<(E + 255) / 256, 256, 0, stream>>>(src, dst, dgO, dgI, gt, E);
  // norms + scan level 1 (fused), then finish scan, then atomic-free fill
  k_norm_scan<<<nblk, 256, 0, stream>>>(dgO, dgI, nO, nI, offs, blks, N);
  k_scan2<<<1, 1024, 0, stream>>>(blks, nblk);
  k_scan3<<<nblk, 256, 0, stream>>>(offs, blks, N);
  k_fill<<<(E + 255) / 256, 256, 0, stream>>>(src, dst, gt, offs, csr, E);

  // h0 = emb[feat] * nO
  k_embed<<<((size_t)N * 16 + 255) / 256, 256, 0, stream>>>(node_feat, emb, nO, h0, N);

  // fused gather+linear, ping-pong h0 <-> h1
  k_gl<<<(N + LIN_NODES - 1) / LIN_NODES, 256, 0, stream>>>(
      h0, csr, offs, dgI, nI, W[0], b[0], h1, N, nO);
  k_gl<<<(N + LIN_NODES - 1) / LIN_NODES, 256, 0, stream>>>(
      h1, csr, offs, dgI, nI, W[1], b[1], h0, N, nO);
  k_gl<<<(N + LIN_NODES - 1) / LIN_NODES, 256, 0, stream>>>(
      h0, csr, offs, dgI, nI, W[2], b[2], h1, N, nullptr);

  k_pool<<<nblk, 256, 0, stream>>>(h1, gid, sums, cnt, N);
  k_div<<<(NGRAPHS * HID + 255) / 256, 256, 0, stream>>>(sums, cnt, out);
}